// Round 1
// baseline (238.395 us; speedup 1.0000x reference)
//
#include <hip/hip_runtime.h>
#include <math.h>

#define BB 32
#define SS 256
#define DD 512
#define FF 1024
#define TT 5
#define K3 1536   // 3*D
#define K4 2048   // 4*D
#define GK 1536

__device__ __forceinline__ float wave_reduce_sum(float x) {
#pragma unroll
  for (int o = 32; o > 0; o >>= 1) x += __shfl_xor(x, o);
  return x;
}
__device__ __forceinline__ float wave_reduce_max(float x) {
#pragma unroll
  for (int o = 32; o > 0; o >>= 1) x = fmaxf(x, __shfl_xor(x, o));
  return x;
}

// ---------------- Kernel A: span [F,1536] and c[F] ----------------
__global__ __launch_bounds__(128)
void span_kernel(const float* __restrict__ en, const int* __restrict__ fb,
                 const int* __restrict__ fs, const int* __restrict__ fe,
                 const float* __restrict__ att_b,
                 float* __restrict__ span, float* __restrict__ cvec)
{
  int f = blockIdx.x;
  int t = threadIdx.x;
  int b = fb[f], s = fs[f], e = fe[f];
  const float* base = en + (size_t)b * SS * DD;
  int d0 = t * 4;
  float4 lw = *(const float4*)(base + (size_t)s * DD + d0);
  float4 rw = *(const float4*)(base + (size_t)(e - 1) * DD + d0);
  float4 wsum = make_float4(0.f, 0.f, 0.f, 0.f);
  for (int p = s; p < e; ++p) {
    float4 m = *(const float4*)(base + (size_t)p * DD + d0);
    wsum.x += m.x; wsum.y += m.y; wsum.z += m.z; wsum.w += m.w;
  }
  float* sp = span + (size_t)f * K3;
  *(float4*)(sp + d0) = lw;
  *(float4*)(sp + DD + d0) = wsum;
  *(float4*)(sp + 2 * DD + d0) = rw;
  // c = span . att_b
  float4 a0 = *(const float4*)(att_b + d0);
  float4 a1 = *(const float4*)(att_b + DD + d0);
  float4 a2 = *(const float4*)(att_b + 2 * DD + d0);
  float part = lw.x*a0.x + lw.y*a0.y + lw.z*a0.z + lw.w*a0.w
             + wsum.x*a1.x + wsum.y*a1.y + wsum.z*a1.z + wsum.w*a1.w
             + rw.x*a2.x + rw.y*a2.y + rw.z*a2.z + rw.w*a2.w;
  part = wave_reduce_sum(part);
  __shared__ float red[2];
  if ((t & 63) == 0) red[t >> 6] = part;
  __syncthreads();
  if (t == 0) cvec[f] = red[0] + red[1];
}

// ---------------- Kernel B: v[F,512] = span[F,1536] @ att_w[1536,512] ----------------
// fp32 vector GEMM, BM=32 BN=64 BK=16, 128 threads, 4x4 per thread, grid (8,32)=256 blocks.
__global__ __launch_bounds__(128)
void gemm_v(const float* __restrict__ A,   // span [1024][1536]
            const float* __restrict__ Bw,  // att_w [1536][512]
            float* __restrict__ C)         // v [1024][512]
{
  const int BM = 32, BN = 64, BK = 16;
  __shared__ float As[BK][36];
  __shared__ float Bs[BK][68];
  int t = threadIdx.x;
  int m0 = blockIdx.y * BM;
  int n0 = blockIdx.x * BN;
  int tm = (t / 16) * 4;   // 0..28
  int tn = (t % 16) * 4;   // 0..60
  float acc[4][4] = {};
  int am = t / 4;          // 0..31
  int ak = (t % 4) * 4;    // 0,4,8,12
  int bq = t % 16;         // float4 group in row
  int bk = t / 16;         // 0..7

  for (int k0 = 0; k0 < GK; k0 += BK) {
    float4 av  = *(const float4*)(A  + (size_t)(m0 + am) * GK + k0 + ak);
    float4 bv0 = *(const float4*)(Bw + (size_t)(k0 + bk) * DD + n0 + bq * 4);
    float4 bv1 = *(const float4*)(Bw + (size_t)(k0 + 8 + bk) * DD + n0 + bq * 4);
    __syncthreads();
    As[ak + 0][am] = av.x;
    As[ak + 1][am] = av.y;
    As[ak + 2][am] = av.z;
    As[ak + 3][am] = av.w;
    *(float4*)(&Bs[bk][bq * 4])     = bv0;
    *(float4*)(&Bs[8 + bk][bq * 4]) = bv1;
    __syncthreads();
#pragma unroll
    for (int k = 0; k < BK; ++k) {
      float4 a = *(float4*)(&As[k][tm]);
      float4 bv = *(float4*)(&Bs[k][tn]);
      acc[0][0] += a.x * bv.x; acc[0][1] += a.x * bv.y; acc[0][2] += a.x * bv.z; acc[0][3] += a.x * bv.w;
      acc[1][0] += a.y * bv.x; acc[1][1] += a.y * bv.y; acc[1][2] += a.y * bv.z; acc[1][3] += a.y * bv.w;
      acc[2][0] += a.z * bv.x; acc[2][1] += a.z * bv.y; acc[2][2] += a.z * bv.z; acc[2][3] += a.z * bv.w;
      acc[3][0] += a.w * bv.x; acc[3][1] += a.w * bv.y; acc[3][2] += a.w * bv.z; acc[3][3] += a.w * bv.w;
    }
  }
#pragma unroll
  for (int i = 0; i < 4; ++i) {
    *(float4*)(C + (size_t)(m0 + tm + i) * DD + n0 + tn) =
        make_float4(acc[i][0], acc[i][1], acc[i][2], acc[i][3]);
  }
}

// ---------------- Kernel C: fused per-fragment scoring ----------------
// scores -> masked softmax -> mix -> logits -> log_softmax
__global__ __launch_bounds__(256)
void frag_kernel(const float* __restrict__ en, const int* __restrict__ lengths,
                 const int* __restrict__ fb, const int* __restrict__ fs,
                 const int* __restrict__ fe,
                 const float* __restrict__ span, const float* __restrict__ cvec,
                 const float* __restrict__ vmat,
                 const float* __restrict__ tag_w, const float* __restrict__ tag_b,
                 float* __restrict__ out)
{
  __shared__ float v_lds[DD];
  __shared__ float sw[SS];       // scores, then att*pw weights, then logit partials
  __shared__ float mix_lds[DD];
  __shared__ float red[8];
  __shared__ float l5[TT];

  int f = blockIdx.x;
  int t = threadIdx.x;
  int lane = t & 63, wv = t >> 6;
  int b = fb[f], s = fs[f], e = fe[f];
  int lenb = lengths[b];
  float seqlen = (float)lengths[0];
  float c = cvec[f];
  const float* mem = en + (size_t)b * SS * DD;

  if (t < 128) *(float4*)(v_lds + t * 4) = *(const float4*)(vmat + (size_t)f * DD + t * 4);
  __syncthreads();

  // ---- Phase A: scores. wave wv handles rows p = wv*64 .. wv*64+63 ----
  {
    float4 va = *(float4*)(v_lds + lane * 8);
    float4 vb = *(float4*)(v_lds + lane * 8 + 4);
    for (int i = 0; i < 64; ++i) {
      int p = wv * 64 + i;
      const float* row = mem + (size_t)p * DD + lane * 8;
      float4 m0 = *(const float4*)(row);
      float4 m1 = *(const float4*)(row + 4);
      float d = m0.x*va.x + m0.y*va.y + m0.z*va.z + m0.w*va.w
              + m1.x*vb.x + m1.y*vb.y + m1.z*vb.z + m1.w*vb.w;
      d = wave_reduce_sum(d);
      if (lane == 0) {
        float dis;
        if (p < s)       dis = (float)(s - p);
        else if (p >= e) dis = (float)(p - e + 1);
        else             dis = seqlen;
        float pw = 1.f - dis / seqlen;
        bool mask = (p >= s && p < e) || (p >= lenb);
        float sc = tanhf(pw * d + c);
        sw[p] = mask ? -1e4f : sc;
      }
    }
  }
  __syncthreads();

  // ---- Phase B: softmax over 256, build weights att*pw ----
  float sc = sw[t];
  float mx = wave_reduce_max(sc);
  if (lane == 0) red[wv] = mx;
  __syncthreads();
  mx = fmaxf(fmaxf(red[0], red[1]), fmaxf(red[2], red[3]));
  float ex = __expf(sc - mx);
  float sm = wave_reduce_sum(ex);
  if (lane == 0) red[4 + wv] = sm;
  __syncthreads();
  sm = red[4] + red[5] + red[6] + red[7];
  {
    int p = t;
    float dis;
    if (p < s)       dis = (float)(s - p);
    else if (p >= e) dis = (float)(p - e + 1);
    else             dis = seqlen;
    float pw = 1.f - dis / seqlen;
    float att = ex / sm;
    __syncthreads();          // everyone done with old sw[t] (own element only, but be safe)
    sw[t] = att * pw;
  }
  __syncthreads();

  // ---- Phase C: mix[d] = sum_p w[p]*memory[p,d]; thread owns d = 2t,2t+1 ----
  {
    float ax = 0.f, ay = 0.f;
#pragma unroll 4
    for (int p = 0; p < SS; ++p) {
      float wgt = sw[p];
      float2 mv = *(const float2*)(mem + (size_t)p * DD + 2 * t);
      ax += wgt * mv.x; ay += wgt * mv.y;
    }
    mix_lds[2 * t]     = ax;
    mix_lds[2 * t + 1] = ay;
  }
  __syncthreads();

  // ---- Phase D: logits[T] = mix_state . tag_w[t] + tag_b, then log_softmax ----
  float vals[8];
  int idx = t * 8;
  if (idx < K3) {
    const float* sp = span + (size_t)f * K3 + idx;
    float4 x0 = *(const float4*)(sp);
    float4 x1 = *(const float4*)(sp + 4);
    vals[0]=x0.x; vals[1]=x0.y; vals[2]=x0.z; vals[3]=x0.w;
    vals[4]=x1.x; vals[5]=x1.y; vals[6]=x1.z; vals[7]=x1.w;
  } else {
#pragma unroll
    for (int j = 0; j < 8; ++j) vals[j] = mix_lds[idx - K3 + j];
  }
  float acc5[TT];
#pragma unroll
  for (int tg = 0; tg < TT; ++tg) {
    const float* twr = tag_w + (size_t)tg * K4 + idx;
    float a = 0.f;
#pragma unroll
    for (int j = 0; j < 8; ++j) a += vals[j] * twr[j];
    acc5[tg] = wave_reduce_sum(a);
  }
  __syncthreads();   // done reading sw as weights
  if (lane == 0) {
#pragma unroll
    for (int tg = 0; tg < TT; ++tg) sw[wv * TT + tg] = acc5[tg];
  }
  __syncthreads();
  if (t < TT) {
    l5[t] = sw[t] + sw[TT + t] + sw[2 * TT + t] + sw[3 * TT + t] + tag_b[t];
  }
  __syncthreads();
  if (t == 0) {
    float m = l5[0];
#pragma unroll
    for (int j = 1; j < TT; ++j) m = fmaxf(m, l5[j]);
    float ssum = 0.f;
#pragma unroll
    for (int j = 0; j < TT; ++j) ssum += __expf(l5[j] - m);
    float lse = m + logf(ssum);
#pragma unroll
    for (int j = 0; j < TT; ++j) out[(size_t)f * TT + j] = l5[j] - lse;
  }
}

extern "C" void kernel_launch(void* const* d_in, const int* in_sizes, int n_in,
                              void* d_out, int out_size, void* d_ws, size_t ws_size,
                              hipStream_t stream) {
  const float* en      = (const float*)d_in[0];
  const int*   lengths = (const int*)d_in[1];
  const int*   frag_b  = (const int*)d_in[2];
  const int*   frag_s  = (const int*)d_in[3];
  const int*   frag_e  = (const int*)d_in[4];
  const float* att_w   = (const float*)d_in[5];
  const float* att_b   = (const float*)d_in[6];
  const float* tag_w   = (const float*)d_in[7];
  const float* tag_b   = (const float*)d_in[8];
  float* out = (float*)d_out;

  float* span = (float*)d_ws;                       // F*1536 floats
  float* cvec = span + (size_t)FF * K3;             // F floats
  float* vmat = cvec + FF;                          // F*512 floats

  span_kernel<<<FF, 128, 0, stream>>>(en, frag_b, frag_s, frag_e, att_b, span, cvec);
  gemm_v<<<dim3(8, 32), 128, 0, stream>>>(span, att_w, vmat);
  frag_kernel<<<FF, 256, 0, stream>>>(en, lengths, frag_b, frag_s, frag_e,
                                      span, cvec, vmat, tag_w, tag_b, out);
}

// Round 3
// 163.130 us; speedup vs baseline: 1.4614x; 1.4614x over previous
//
#include <hip/hip_runtime.h>
#include <math.h>

#define BB 32
#define SS 256
#define DD 512
#define FF 1024
#define TT 5
#define K3 1536   // 3*D
#define K4 2048   // 4*D
#define GK 1536
#define SK 4      // split-K factor for gemm_v
#define KCH (GK / SK)   // 384

__device__ __forceinline__ float wave_reduce_sum(float x) {
#pragma unroll
  for (int o = 32; o > 0; o >>= 1) x += __shfl_xor(x, o);
  return x;
}

// ---------------- Kernel A: span [F,1536] and c[F] ----------------
__global__ __launch_bounds__(128)
void span_kernel(const float* __restrict__ en, const int* __restrict__ fb,
                 const int* __restrict__ fs, const int* __restrict__ fe,
                 const float* __restrict__ att_b,
                 float* __restrict__ span, float* __restrict__ cvec)
{
  int f = blockIdx.x;
  int t = threadIdx.x;
  int b = fb[f], s = fs[f], e = fe[f];
  const float* base = en + (size_t)b * SS * DD;
  int d0 = t * 4;
  float4 lw = *(const float4*)(base + (size_t)s * DD + d0);
  float4 rw = *(const float4*)(base + (size_t)(e - 1) * DD + d0);
  float4 wsum = make_float4(0.f, 0.f, 0.f, 0.f);
  for (int p = s; p < e; ++p) {
    float4 m = *(const float4*)(base + (size_t)p * DD + d0);
    wsum.x += m.x; wsum.y += m.y; wsum.z += m.z; wsum.w += m.w;
  }
  float* sp = span + (size_t)f * K3;
  *(float4*)(sp + d0) = lw;
  *(float4*)(sp + DD + d0) = wsum;
  *(float4*)(sp + 2 * DD + d0) = rw;
  // c = span . att_b
  float4 a0 = *(const float4*)(att_b + d0);
  float4 a1 = *(const float4*)(att_b + DD + d0);
  float4 a2 = *(const float4*)(att_b + 2 * DD + d0);
  float part = lw.x*a0.x + lw.y*a0.y + lw.z*a0.z + lw.w*a0.w
             + wsum.x*a1.x + wsum.y*a1.y + wsum.z*a1.z + wsum.w*a1.w
             + rw.x*a2.x + rw.y*a2.y + rw.z*a2.z + rw.w*a2.w;
  part = wave_reduce_sum(part);
  __shared__ float red[2];
  if ((t & 63) == 0) red[t >> 6] = part;
  __syncthreads();
  if (t == 0) cvec[f] = red[0] + red[1];
}

// ---------------- Kernel B: v partials = span @ att_w, split-K ----------------
// BM=32 BN=64 BK=16, 256 threads (4 waves), 2x4 per thread, grid (8,32,4)=1024 blocks.
__global__ __launch_bounds__(256)
void gemm_v(const float* __restrict__ A,    // span [1024][1536]
            const float* __restrict__ Bw,   // att_w [1536][512]
            float* __restrict__ Cpart)      // [SK][1024][512]
{
  const int BM = 32, BN = 64, BK = 16;
  __shared__ float As[BK][BM + 2];
  __shared__ float Bs[BK][BN + 4];
  int t = threadIdx.x;
  int n0 = blockIdx.x * BN;
  int m0 = blockIdx.y * BM;
  int sk = blockIdx.z;
  int kbase = sk * KCH;

  int ar = t >> 3;          // 0..31  A row
  int ac = (t & 7) * 2;     // 0..14  A col pair
  int br = t >> 4;          // 0..15  B row
  int bc = (t & 15) * 4;    // 0..60  B col quad
  int tm = (t >> 4) * 2;    // 0..30
  int tn = (t & 15) * 4;    // 0..60

  float acc[2][4] = {};

  for (int k0 = kbase; k0 < kbase + KCH; k0 += BK) {
    float2 av = *(const float2*)(A + (size_t)(m0 + ar) * GK + k0 + ac);
    float4 bv = *(const float4*)(Bw + (size_t)(k0 + br) * DD + n0 + bc);
    __syncthreads();
    As[ac][ar] = av.x;
    As[ac + 1][ar] = av.y;
    *(float4*)(&Bs[br][bc]) = bv;
    __syncthreads();
#pragma unroll
    for (int k = 0; k < BK; ++k) {
      float a0 = As[k][tm], a1 = As[k][tm + 1];
      float4 b = *(float4*)(&Bs[k][tn]);
      acc[0][0] += a0 * b.x; acc[0][1] += a0 * b.y; acc[0][2] += a0 * b.z; acc[0][3] += a0 * b.w;
      acc[1][0] += a1 * b.x; acc[1][1] += a1 * b.y; acc[1][2] += a1 * b.z; acc[1][3] += a1 * b.w;
    }
  }
  float* Cp = Cpart + (size_t)sk * FF * DD;
#pragma unroll
  for (int i = 0; i < 2; ++i) {
    *(float4*)(Cp + (size_t)(m0 + tm + i) * DD + n0 + tn) =
        make_float4(acc[i][0], acc[i][1], acc[i][2], acc[i][3]);
  }
}

// ---------------- Kernel C: fused single-pass per-fragment ----------------
// online-softmax: scores + softmax + mix in ONE read of memory, then logits.
__global__ __launch_bounds__(256)
void frag_kernel(const float* __restrict__ en, const int* __restrict__ lengths,
                 const int* __restrict__ fb, const int* __restrict__ fs,
                 const int* __restrict__ fe,
                 const float* __restrict__ span, const float* __restrict__ cvec,
                 const float* __restrict__ vpart,
                 const float* __restrict__ tag_w, const float* __restrict__ tag_b,
                 float* __restrict__ out)
{
  __shared__ float v_lds[DD];
  __shared__ float buf[4][DD];     // per-wave scaled mix partials
  __shared__ float mstate[4][2];   // per-wave (m, ssum)
  __shared__ float mix_lds[DD];
  __shared__ float pl[4 * TT];
  __shared__ float l5[TT];

  int f = blockIdx.x;
  int t = threadIdx.x;
  int lane = t & 63, wv = t >> 6;
  int b = fb[f], s = fs[f], e = fe[f];
  int lenb = lengths[b];
  float seqlen = (float)lengths[0];
  float c = cvec[f];
  const float* mem = en + (size_t)b * SS * DD;

  // v = sum of split-K partials
  if (t < 128) {
    float4 v0 = *(const float4*)(vpart + (size_t)f * DD + t * 4);
    float4 v1 = *(const float4*)(vpart + (size_t)FF * DD + (size_t)f * DD + t * 4);
    float4 v2 = *(const float4*)(vpart + 2 * (size_t)FF * DD + (size_t)f * DD + t * 4);
    float4 v3 = *(const float4*)(vpart + 3 * (size_t)FF * DD + (size_t)f * DD + t * 4);
    *(float4*)(v_lds + t * 4) = make_float4(v0.x + v1.x + v2.x + v3.x,
                                            v0.y + v1.y + v2.y + v3.y,
                                            v0.z + v1.z + v2.z + v3.z,
                                            v0.w + v1.w + v2.w + v3.w);
  }
  __syncthreads();

  // ---- single pass: online softmax + mix accumulation ----
  float4 va = *(float4*)(v_lds + lane * 8);
  float4 vb = *(float4*)(v_lds + lane * 8 + 4);
  float m = -1e30f, ssum = 0.f;
  float am[8] = {0.f, 0.f, 0.f, 0.f, 0.f, 0.f, 0.f, 0.f};

  for (int i = 0; i < 64; ++i) {
    int p = wv * 64 + i;
    const float* row = mem + (size_t)p * DD + lane * 8;
    float4 r0 = *(const float4*)(row);
    float4 r1 = *(const float4*)(row + 4);
    float d = r0.x*va.x + r0.y*va.y + r0.z*va.z + r0.w*va.w
            + r1.x*vb.x + r1.y*vb.y + r1.z*vb.z + r1.w*vb.w;
    d = wave_reduce_sum(d);            // broadcast to all lanes
    bool mask = (p >= s && p < e) || (p >= lenb);
    if (!mask) {                       // wave-uniform branch
      float dis = (p < s) ? (float)(s - p) : (float)(p - e + 1);
      float pw = 1.f - dis / seqlen;
      float sc = tanhf(pw * d + c);
      if (sc > m) {                    // wave-uniform rescale
        float scale = __expf(m - sc);
        ssum *= scale;
#pragma unroll
        for (int j = 0; j < 8; ++j) am[j] *= scale;
        m = sc;
      }
      float u = __expf(sc - m);
      ssum += u;
      float upw = u * pw;
      am[0] += upw * r0.x; am[1] += upw * r0.y; am[2] += upw * r0.z; am[3] += upw * r0.w;
      am[4] += upw * r1.x; am[5] += upw * r1.y; am[6] += upw * r1.z; am[7] += upw * r1.w;
    }
  }
  if (lane == 0) { mstate[wv][0] = m; mstate[wv][1] = ssum; }
  __syncthreads();
  float M = fmaxf(fmaxf(mstate[0][0], mstate[1][0]), fmaxf(mstate[2][0], mstate[3][0]));
  float S = mstate[0][1] * __expf(mstate[0][0] - M)
          + mstate[1][1] * __expf(mstate[1][0] - M)
          + mstate[2][1] * __expf(mstate[2][0] - M)
          + mstate[3][1] * __expf(mstate[3][0] - M);
  float ew = __expf(m - M);
  {
    float4 s0 = make_float4(am[0] * ew, am[1] * ew, am[2] * ew, am[3] * ew);
    float4 s1 = make_float4(am[4] * ew, am[5] * ew, am[6] * ew, am[7] * ew);
    *(float4*)(&buf[wv][lane * 8]) = s0;
    *(float4*)(&buf[wv][lane * 8 + 4]) = s1;
  }
  __syncthreads();
  {
    int d0 = t * 2;
    float inv = 1.f / S;
    mix_lds[d0]     = (buf[0][d0] + buf[1][d0] + buf[2][d0] + buf[3][d0]) * inv;
    mix_lds[d0 + 1] = (buf[0][d0 + 1] + buf[1][d0 + 1] + buf[2][d0 + 1] + buf[3][d0 + 1]) * inv;
  }
  __syncthreads();

  // ---- logits + log_softmax ----
  float vals[8];
  int idx = t * 8;
  if (idx < K3) {
    const float* sp = span + (size_t)f * K3 + idx;
    float4 x0 = *(const float4*)(sp);
    float4 x1 = *(const float4*)(sp + 4);
    vals[0]=x0.x; vals[1]=x0.y; vals[2]=x0.z; vals[3]=x0.w;
    vals[4]=x1.x; vals[5]=x1.y; vals[6]=x1.z; vals[7]=x1.w;
  } else {
#pragma unroll
    for (int j = 0; j < 8; ++j) vals[j] = mix_lds[idx - K3 + j];
  }
  float acc5[TT];
#pragma unroll
  for (int tg = 0; tg < TT; ++tg) {
    const float* twr = tag_w + (size_t)tg * K4 + idx;
    float a = 0.f;
#pragma unroll
    for (int j = 0; j < 8; ++j) a += vals[j] * twr[j];
    acc5[tg] = wave_reduce_sum(a);
  }
  if (lane == 0) {
#pragma unroll
    for (int tg = 0; tg < TT; ++tg) pl[wv * TT + tg] = acc5[tg];
  }
  __syncthreads();
  if (t < TT) {
    l5[t] = pl[t] + pl[TT + t] + pl[2 * TT + t] + pl[3 * TT + t] + tag_b[t];
  }
  __syncthreads();
  if (t == 0) {
    float mm = l5[0];
#pragma unroll
    for (int j = 1; j < TT; ++j) mm = fmaxf(mm, l5[j]);
    float se = 0.f;
#pragma unroll
    for (int j = 0; j < TT; ++j) se += __expf(l5[j] - mm);
    float lse = mm + logf(se);
#pragma unroll
    for (int j = 0; j < TT; ++j) out[(size_t)f * TT + j] = l5[j] - lse;
  }
}

extern "C" void kernel_launch(void* const* d_in, const int* in_sizes, int n_in,
                              void* d_out, int out_size, void* d_ws, size_t ws_size,
                              hipStream_t stream) {
  const float* en      = (const float*)d_in[0];
  const int*   lengths = (const int*)d_in[1];
  const int*   frag_b  = (const int*)d_in[2];
  const int*   frag_s  = (const int*)d_in[3];
  const int*   frag_e  = (const int*)d_in[4];
  const float* att_w   = (const float*)d_in[5];
  const float* att_b   = (const float*)d_in[6];
  const float* tag_w   = (const float*)d_in[7];
  const float* tag_b   = (const float*)d_in[8];
  float* out = (float*)d_out;

  float* span  = (float*)d_ws;                      // F*1536
  float* cvec  = span + (size_t)FF * K3;            // F
  float* vpart = cvec + FF;                         // SK*F*512

  span_kernel<<<FF, 128, 0, stream>>>(en, frag_b, frag_s, frag_e, att_b, span, cvec);
  gemm_v<<<dim3(8, 32, SK), 256, 0, stream>>>(span, att_w, vpart);
  frag_kernel<<<FF, 256, 0, stream>>>(en, lengths, frag_b, frag_s, frag_e,
                                      span, cvec, vpart, tag_w, tag_b, out);
}

// Round 5
// 159.360 us; speedup vs baseline: 1.4959x; 1.0237x over previous
//
#include <hip/hip_runtime.h>
#include <math.h>

#define BB 32
#define SS 256
#define DD 512
#define FF 1024
#define TT 5
#define K3 1536   // 3*D
#define K4 2048   // 4*D
#define GK 1536
#define SK 4      // split-K factor for gemm_v
#define KCH (GK / SK)   // 384

__device__ __forceinline__ float wave_reduce_sum(float x) {
#pragma unroll
  for (int o = 32; o > 0; o >>= 1) x += __shfl_xor(x, o);
  return x;
}

// exp-based tanh: ~8 instrs vs library tanhf's branchy range handling.
// |err| vs tanhf < 1e-6 — negligible against the 3.9e-3 absmax budget.
__device__ __forceinline__ float fast_tanh(float x) {
  float ax = fabsf(x);
  float t = __expf(-2.f * ax);
  float r = (1.f - t) / (1.f + t);
  return x < 0.f ? -r : r;
}

// ---------------- Kernel 0: bucket fragments by sentence ----------------
// order[] = frag ids sorted by frag_b (order within a bucket is arbitrary —
// each fragment's output is independent, so any order is correct).
__global__ __launch_bounds__(1024)
void bucket_kernel(const int* __restrict__ fb, int* __restrict__ order) {
  __shared__ int cnt[BB];
  __shared__ int start[BB];
  int t = threadIdx.x;
  if (t < BB) cnt[t] = 0;
  __syncthreads();
  int b = fb[t];
  int r = atomicAdd(&cnt[b], 1);
  __syncthreads();
  if (t == 0) {
    int acc = 0;
    for (int i = 0; i < BB; ++i) { start[i] = acc; acc += cnt[i]; }
  }
  __syncthreads();
  order[start[b] + r] = t;
}

// ---------------- Kernel A: span [F,1536] and c[F] ----------------
__global__ __launch_bounds__(128)
void span_kernel(const float* __restrict__ en, const int* __restrict__ fb,
                 const int* __restrict__ fs, const int* __restrict__ fe,
                 const float* __restrict__ att_b,
                 float* __restrict__ span, float* __restrict__ cvec)
{
  int f = blockIdx.x;
  int t = threadIdx.x;
  int b = fb[f], s = fs[f], e = fe[f];
  const float* base = en + (size_t)b * SS * DD;
  int d0 = t * 4;
  float4 lw = *(const float4*)(base + (size_t)s * DD + d0);
  float4 rw = *(const float4*)(base + (size_t)(e - 1) * DD + d0);
  float4 wsum = make_float4(0.f, 0.f, 0.f, 0.f);
  for (int p = s; p < e; ++p) {
    float4 m = *(const float4*)(base + (size_t)p * DD + d0);
    wsum.x += m.x; wsum.y += m.y; wsum.z += m.z; wsum.w += m.w;
  }
  float* sp = span + (size_t)f * K3;
  *(float4*)(sp + d0) = lw;
  *(float4*)(sp + DD + d0) = wsum;
  *(float4*)(sp + 2 * DD + d0) = rw;
  float4 a0 = *(const float4*)(att_b + d0);
  float4 a1 = *(const float4*)(att_b + DD + d0);
  float4 a2 = *(const float4*)(att_b + 2 * DD + d0);
  float part = lw.x*a0.x + lw.y*a0.y + lw.z*a0.z + lw.w*a0.w
             + wsum.x*a1.x + wsum.y*a1.y + wsum.z*a1.z + wsum.w*a1.w
             + rw.x*a2.x + rw.y*a2.y + rw.z*a2.z + rw.w*a2.w;
  part = wave_reduce_sum(part);
  __shared__ float red[2];
  if ((t & 63) == 0) red[t >> 6] = part;
  __syncthreads();
  if (t == 0) cvec[f] = red[0] + red[1];
}

// ---------------- Kernel B: v partials = span @ att_w, split-K ----------------
__global__ __launch_bounds__(256)
void gemm_v(const float* __restrict__ A,    // span [1024][1536]
            const float* __restrict__ Bw,   // att_w [1536][512]
            float* __restrict__ Cpart)      // [SK][1024][512]
{
  const int BM = 32, BN = 64, BK = 16;
  __shared__ float As[BK][BM + 2];
  __shared__ float Bs[BK][BN + 4];
  int t = threadIdx.x;
  int n0 = blockIdx.x * BN;
  int m0 = blockIdx.y * BM;
  int sk = blockIdx.z;
  int kbase = sk * KCH;

  int ar = t >> 3;
  int ac = (t & 7) * 2;
  int br = t >> 4;
  int bc = (t & 15) * 4;
  int tm = (t >> 4) * 2;
  int tn = (t & 15) * 4;

  float acc[2][4] = {};

  for (int k0 = kbase; k0 < kbase + KCH; k0 += BK) {
    float2 av = *(const float2*)(A + (size_t)(m0 + ar) * GK + k0 + ac);
    float4 bv = *(const float4*)(Bw + (size_t)(k0 + br) * DD + n0 + bc);
    __syncthreads();
    As[ac][ar] = av.x;
    As[ac + 1][ar] = av.y;
    *(float4*)(&Bs[br][bc]) = bv;
    __syncthreads();
#pragma unroll
    for (int k = 0; k < BK; ++k) {
      float a0 = As[k][tm], a1 = As[k][tm + 1];
      float4 b = *(float4*)(&Bs[k][tn]);
      acc[0][0] += a0 * b.x; acc[0][1] += a0 * b.y; acc[0][2] += a0 * b.z; acc[0][3] += a0 * b.w;
      acc[1][0] += a1 * b.x; acc[1][1] += a1 * b.y; acc[1][2] += a1 * b.z; acc[1][3] += a1 * b.w;
    }
  }
  float* Cp = Cpart + (size_t)sk * FF * DD;
#pragma unroll
  for (int i = 0; i < 2; ++i) {
    *(float4*)(Cp + (size_t)(m0 + tm + i) * DD + n0 + tn) =
        make_float4(acc[i][0], acc[i][1], acc[i][2], acc[i][3]);
  }
}

// ---------------- Kernel C: fused single-pass per-fragment ----------------
// XCD-striped fragment assignment: block bid processes order[(bid&7)*128+(bid>>3)]
// so XCD x (bid%8==x under round-robin dispatch) sees a contiguous chunk of the
// b-sorted fragment list (~4 sentences = 2 MB, resident in its 4 MB L2).
// Rows batched x8 so the 6-step shuffle-reduce chains interleave.
__global__ __launch_bounds__(256)
void frag_kernel(const float* __restrict__ en, const int* __restrict__ lengths,
                 const int* __restrict__ fb, const int* __restrict__ fs,
                 const int* __restrict__ fe,
                 const float* __restrict__ span, const float* __restrict__ cvec,
                 const float* __restrict__ vpart,
                 const float* __restrict__ tag_w, const float* __restrict__ tag_b,
                 const int* __restrict__ order,
                 float* __restrict__ out)
{
  __shared__ float v_lds[DD];
  __shared__ float buf[4][DD];
  __shared__ float mstate[4][2];
  __shared__ float mix_lds[DD];
  __shared__ float pl[4 * TT];
  __shared__ float l5[TT];

  int bid = blockIdx.x;
  int f = order[(bid & 7) * (FF / 8) + (bid >> 3)];
  int t = threadIdx.x;
  int lane = t & 63, wv = t >> 6;
  int b = fb[f], s = fs[f], e = fe[f];
  int lenb = lengths[b];
  float seqlen = (float)lengths[0];
  float c = cvec[f];
  const float* mem = en + (size_t)b * SS * DD;

  if (t < 128) {
    float4 v0 = *(const float4*)(vpart + (size_t)f * DD + t * 4);
    float4 v1 = *(const float4*)(vpart + (size_t)FF * DD + (size_t)f * DD + t * 4);
    float4 v2 = *(const float4*)(vpart + 2 * (size_t)FF * DD + (size_t)f * DD + t * 4);
    float4 v3 = *(const float4*)(vpart + 3 * (size_t)FF * DD + (size_t)f * DD + t * 4);
    *(float4*)(v_lds + t * 4) = make_float4(v0.x + v1.x + v2.x + v3.x,
                                            v0.y + v1.y + v2.y + v3.y,
                                            v0.z + v1.z + v2.z + v3.z,
                                            v0.w + v1.w + v2.w + v3.w);
  }
  __syncthreads();

  float4 va = *(float4*)(v_lds + lane * 8);
  float4 vb = *(float4*)(v_lds + lane * 8 + 4);
  float m = -1e30f, ssum = 0.f;
  float am[8] = {0.f, 0.f, 0.f, 0.f, 0.f, 0.f, 0.f, 0.f};

  for (int i0 = 0; i0 < 64; i0 += 8) {
    float4 R0[8], R1[8];
    float d8[8];
    // batch loads + per-lane partial dots (8 independent)
#pragma unroll
    for (int k = 0; k < 8; ++k) {
      int p = wv * 64 + i0 + k;
      const float* row = mem + (size_t)p * DD + lane * 8;
      R0[k] = *(const float4*)(row);
      R1[k] = *(const float4*)(row + 4);
      d8[k] = R0[k].x*va.x + R0[k].y*va.y + R0[k].z*va.z + R0[k].w*va.w
            + R1[k].x*vb.x + R1[k].y*vb.y + R1[k].z*vb.z + R1[k].w*vb.w;
    }
    // 8 interleaved butterfly reduces — chains independent, latency pipelined
#pragma unroll
    for (int o = 32; o > 0; o >>= 1) {
#pragma unroll
      for (int k = 0; k < 8; ++k) d8[k] += __shfl_xor(d8[k], o);
    }
    // online-softmax updates (wave-uniform branches)
#pragma unroll
    for (int k = 0; k < 8; ++k) {
      int p = wv * 64 + i0 + k;
      bool mask = (p >= s && p < e) || (p >= lenb);
      if (!mask) {
        float dis = (p < s) ? (float)(s - p) : (float)(p - e + 1);
        float pw = 1.f - dis / seqlen;
        float sc = fast_tanh(pw * d8[k] + c);
        if (sc > m) {
          float scale = __expf(m - sc);
          ssum *= scale;
#pragma unroll
          for (int j = 0; j < 8; ++j) am[j] *= scale;
          m = sc;
        }
        float u = __expf(sc - m);
        ssum += u;
        float upw = u * pw;
        am[0] += upw * R0[k].x; am[1] += upw * R0[k].y; am[2] += upw * R0[k].z; am[3] += upw * R0[k].w;
        am[4] += upw * R1[k].x; am[5] += upw * R1[k].y; am[6] += upw * R1[k].z; am[7] += upw * R1[k].w;
      }
    }
  }
  if (lane == 0) { mstate[wv][0] = m; mstate[wv][1] = ssum; }
  __syncthreads();
  float M = fmaxf(fmaxf(mstate[0][0], mstate[1][0]), fmaxf(mstate[2][0], mstate[3][0]));
  float S = mstate[0][1] * __expf(mstate[0][0] - M)
          + mstate[1][1] * __expf(mstate[1][0] - M)
          + mstate[2][1] * __expf(mstate[2][0] - M)
          + mstate[3][1] * __expf(mstate[3][0] - M);
  float ew = __expf(m - M);
  {
    float4 s0 = make_float4(am[0] * ew, am[1] * ew, am[2] * ew, am[3] * ew);
    float4 s1 = make_float4(am[4] * ew, am[5] * ew, am[6] * ew, am[7] * ew);
    *(float4*)(&buf[wv][lane * 8]) = s0;
    *(float4*)(&buf[wv][lane * 8 + 4]) = s1;
  }
  __syncthreads();
  {
    int d0 = t * 2;
    float inv = 1.f / S;
    mix_lds[d0]     = (buf[0][d0] + buf[1][d0] + buf[2][d0] + buf[3][d0]) * inv;
    mix_lds[d0 + 1] = (buf[0][d0 + 1] + buf[1][d0 + 1] + buf[2][d0 + 1] + buf[3][d0 + 1]) * inv;
  }
  __syncthreads();

  // ---- logits + log_softmax ----
  float vals[8];
  int idx = t * 8;
  if (idx < K3) {
    const float* sp = span + (size_t)f * K3 + idx;
    float4 x0 = *(const float4*)(sp);
    float4 x1 = *(const float4*)(sp + 4);
    vals[0]=x0.x; vals[1]=x0.y; vals[2]=x0.z; vals[3]=x0.w;
    vals[4]=x1.x; vals[5]=x1.y; vals[6]=x1.z; vals[7]=x1.w;
  } else {
#pragma unroll
    for (int j = 0; j < 8; ++j) vals[j] = mix_lds[idx - K3 + j];
  }
  float acc5[TT];
#pragma unroll
  for (int tg = 0; tg < TT; ++tg) {
    const float* twr = tag_w + (size_t)tg * K4 + idx;
    float a = 0.f;
#pragma unroll
    for (int j = 0; j < 8; ++j) a += vals[j] * twr[j];
    acc5[tg] = wave_reduce_sum(a);
  }
  if (lane == 0) {
#pragma unroll
    for (int tg = 0; tg < TT; ++tg) pl[wv * TT + tg] = acc5[tg];
  }
  __syncthreads();
  if (t < TT) {
    l5[t] = pl[t] + pl[TT + t] + pl[2 * TT + t] + pl[3 * TT + t] + tag_b[t];
  }
  __syncthreads();
  if (t == 0) {
    float mm = l5[0];
#pragma unroll
    for (int j = 1; j < TT; ++j) mm = fmaxf(mm, l5[j]);
    float se = 0.f;
#pragma unroll
    for (int j = 0; j < TT; ++j) se += __expf(l5[j] - mm);
    float lse = mm + logf(se);
#pragma unroll
    for (int j = 0; j < TT; ++j) out[(size_t)f * TT + j] = l5[j] - lse;
  }
}

extern "C" void kernel_launch(void* const* d_in, const int* in_sizes, int n_in,
                              void* d_out, int out_size, void* d_ws, size_t ws_size,
                              hipStream_t stream) {
  const float* en      = (const float*)d_in[0];
  const int*   lengths = (const int*)d_in[1];
  const int*   frag_b  = (const int*)d_in[2];
  const int*   frag_s  = (const int*)d_in[3];
  const int*   frag_e  = (const int*)d_in[4];
  const float* att_w   = (const float*)d_in[5];
  const float* att_b   = (const float*)d_in[6];
  const float* tag_w   = (const float*)d_in[7];
  const float* tag_b   = (const float*)d_in[8];
  float* out = (float*)d_out;

  float* span  = (float*)d_ws;                      // F*1536
  float* cvec  = span + (size_t)FF * K3;            // F
  float* vpart = cvec + FF;                         // SK*F*512
  int*   order = (int*)(vpart + (size_t)SK * FF * DD);  // F ints

  bucket_kernel<<<1, FF, 0, stream>>>(frag_b, order);
  span_kernel<<<FF, 128, 0, stream>>>(en, frag_b, frag_s, frag_e, att_b, span, cvec);
  gemm_v<<<dim3(8, 32, SK), 256, 0, stream>>>(span, att_w, vpart);
  frag_kernel<<<FF, 256, 0, stream>>>(en, lengths, frag_b, frag_s, frag_e,
                                      span, cvec, vpart, tag_w, tag_b, order, out);
}

// Round 7
// 156.239 us; speedup vs baseline: 1.5258x; 1.0200x over previous
//
#include <hip/hip_runtime.h>
#include <math.h>

#define BB 32
#define SS 256
#define DD 512
#define FF 1024
#define TT 5
#define K3 1536   // 3*D
#define K4 2048   // 4*D
#define GK 1536
#define SK 4      // split-K factor for gemm_v
#define KCH (GK / SK)   // 384

__device__ __forceinline__ float wave_reduce_sum(float x) {
#pragma unroll
  for (int o = 32; o > 0; o >>= 1) x += __shfl_xor(x, o);
  return x;
}

// exp-based tanh: ~8 instrs vs library tanhf's branchy range handling.
__device__ __forceinline__ float fast_tanh(float x) {
  float ax = fabsf(x);
  float t = __expf(-2.f * ax);
  float r = (1.f - t) / (1.f + t);
  return x < 0.f ? -r : r;
}

// ---------------- Kernel 0: bucket fragments by sentence ----------------
__global__ __launch_bounds__(1024)
void bucket_kernel(const int* __restrict__ fb, int* __restrict__ order) {
  __shared__ int cnt[BB];
  __shared__ int start[BB];
  int t = threadIdx.x;
  if (t < BB) cnt[t] = 0;
  __syncthreads();
  int b = fb[t];
  int r = atomicAdd(&cnt[b], 1);
  __syncthreads();
  if (t == 0) {
    int acc = 0;
    for (int i = 0; i < BB; ++i) { start[i] = acc; acc += cnt[i]; }
  }
  __syncthreads();
  order[start[b] + r] = t;
}

// ---------------- Kernel A: span [F,1536] and c[F] (XCD-striped) ----------------
__global__ __launch_bounds__(128)
void span_kernel(const float* __restrict__ en, const int* __restrict__ fb,
                 const int* __restrict__ fs, const int* __restrict__ fe,
                 const float* __restrict__ att_b, const int* __restrict__ order,
                 float* __restrict__ span, float* __restrict__ cvec)
{
  int bid = blockIdx.x;
  int f = order[(bid & 7) * (FF / 8) + (bid >> 3)];
  int t = threadIdx.x;
  int b = fb[f], s = fs[f], e = fe[f];
  const float* base = en + (size_t)b * SS * DD;
  int d0 = t * 4;
  float4 lw = *(const float4*)(base + (size_t)s * DD + d0);
  float4 rw = *(const float4*)(base + (size_t)(e - 1) * DD + d0);
  float4 wsum = make_float4(0.f, 0.f, 0.f, 0.f);
  for (int p = s; p < e; ++p) {
    float4 m = *(const float4*)(base + (size_t)p * DD + d0);
    wsum.x += m.x; wsum.y += m.y; wsum.z += m.z; wsum.w += m.w;
  }
  float* sp = span + (size_t)f * K3;
  *(float4*)(sp + d0) = lw;
  *(float4*)(sp + DD + d0) = wsum;
  *(float4*)(sp + 2 * DD + d0) = rw;
  float4 a0 = *(const float4*)(att_b + d0);
  float4 a1 = *(const float4*)(att_b + DD + d0);
  float4 a2 = *(const float4*)(att_b + 2 * DD + d0);
  float part = lw.x*a0.x + lw.y*a0.y + lw.z*a0.z + lw.w*a0.w
             + wsum.x*a1.x + wsum.y*a1.y + wsum.z*a1.z + wsum.w*a1.w
             + rw.x*a2.x + rw.y*a2.y + rw.z*a2.z + rw.w*a2.w;
  part = wave_reduce_sum(part);
  __shared__ float red[2];
  if ((t & 63) == 0) red[t >> 6] = part;
  __syncthreads();
  if (t == 0) cvec[f] = red[0] + red[1];
}

// ---------------- Kernel B: v partials = span @ att_w, split-K ----------------
// BM=64 BN=64 BK=16, 256 threads, 4x4/thread, both operands ds_read_b128.
__global__ __launch_bounds__(256)
void gemm_v(const float* __restrict__ A,    // span [1024][1536]
            const float* __restrict__ Bw,   // att_w [1536][512]
            float* __restrict__ Cpart)      // [SK][1024][512]
{
  const int BM = 64, BN = 64, BK = 16;
  __shared__ float As[BK][BM + 4];   // stride 68 floats: 16B-aligned float4 rows
  __shared__ float Bs[BK][BN + 4];
  int t = threadIdx.x;
  int n0 = blockIdx.x * BN;          // grid.x = 8
  int m0 = blockIdx.y * BM;          // grid.y = 16
  int kbase = blockIdx.z * KCH;

  int ar = t >> 2;          // 0..63  A row
  int ac = (t & 3) * 4;     // 0,4,8,12
  int br = t >> 4;          // 0..15  B k-row
  int bc = (t & 15) * 4;    // 0..60
  int tm = (t >> 4) * 4;    // 0..60
  int tn = (t & 15) * 4;    // 0..60

  float acc[4][4] = {};

  for (int k0 = kbase; k0 < kbase + KCH; k0 += BK) {
    float4 av = *(const float4*)(A  + (size_t)(m0 + ar) * GK + k0 + ac);
    float4 bv = *(const float4*)(Bw + (size_t)(k0 + br) * DD + n0 + bc);
    __syncthreads();
    As[ac + 0][ar] = av.x;
    As[ac + 1][ar] = av.y;
    As[ac + 2][ar] = av.z;
    As[ac + 3][ar] = av.w;
    *(float4*)(&Bs[br][bc]) = bv;
    __syncthreads();
#pragma unroll
    for (int k = 0; k < BK; ++k) {
      float4 a = *(float4*)(&As[k][tm]);
      float4 b = *(float4*)(&Bs[k][tn]);
      acc[0][0] += a.x * b.x; acc[0][1] += a.x * b.y; acc[0][2] += a.x * b.z; acc[0][3] += a.x * b.w;
      acc[1][0] += a.y * b.x; acc[1][1] += a.y * b.y; acc[1][2] += a.y * b.z; acc[1][3] += a.y * b.w;
      acc[2][0] += a.z * b.x; acc[2][1] += a.z * b.y; acc[2][2] += a.z * b.z; acc[2][3] += a.z * b.w;
      acc[3][0] += a.w * b.x; acc[3][1] += a.w * b.y; acc[3][2] += a.w * b.z; acc[3][3] += a.w * b.w;
    }
  }
  float* Cp = Cpart + (size_t)blockIdx.z * FF * DD;
#pragma unroll
  for (int i = 0; i < 4; ++i) {
    *(float4*)(Cp + (size_t)(m0 + tm + i) * DD + n0 + tn) =
        make_float4(acc[i][0], acc[i][1], acc[i][2], acc[i][3]);
  }
}

// ---------------- Kernel C: fused single-pass per-fragment ----------------
// XCD-striped; rows p >= lengths[b] skipped entirely (exact: their exp
// underflows to 0 in the reference). ~25% fewer rows on average.
__global__ __launch_bounds__(256)
void frag_kernel(const float* __restrict__ en, const int* __restrict__ lengths,
                 const int* __restrict__ fb, const int* __restrict__ fs,
                 const int* __restrict__ fe,
                 const float* __restrict__ span, const float* __restrict__ cvec,
                 const float* __restrict__ vpart,
                 const float* __restrict__ tag_w, const float* __restrict__ tag_b,
                 const int* __restrict__ order,
                 float* __restrict__ out)
{
  __shared__ float v_lds[DD];
  __shared__ float buf[4][DD];
  __shared__ float mstate[4][2];
  __shared__ float mix_lds[DD];
  __shared__ float pl[4 * TT];
  __shared__ float l5[TT];

  int bid = blockIdx.x;
  int f = order[(bid & 7) * (FF / 8) + (bid >> 3)];
  int t = threadIdx.x;
  int lane = t & 63, wv = t >> 6;
  int b = fb[f], s = fs[f], e = fe[f];
  int lenb = lengths[b];
  float seqlen = (float)lengths[0];
  float c = cvec[f];
  const float* mem = en + (size_t)b * SS * DD;

  if (t < 128) {
    float4 v0 = *(const float4*)(vpart + (size_t)f * DD + t * 4);
    float4 v1 = *(const float4*)(vpart + (size_t)FF * DD + (size_t)f * DD + t * 4);
    float4 v2 = *(const float4*)(vpart + 2 * (size_t)FF * DD + (size_t)f * DD + t * 4);
    float4 v3 = *(const float4*)(vpart + 3 * (size_t)FF * DD + (size_t)f * DD + t * 4);
    *(float4*)(v_lds + t * 4) = make_float4(v0.x + v1.x + v2.x + v3.x,
                                            v0.y + v1.y + v2.y + v3.y,
                                            v0.z + v1.z + v2.z + v3.z,
                                            v0.w + v1.w + v2.w + v3.w);
  }
  __syncthreads();

  float4 va = *(float4*)(v_lds + lane * 8);
  float4 vb = *(float4*)(v_lds + lane * 8 + 4);
  float m = -1e30f, ssum = 0.f;
  float am[8] = {0.f, 0.f, 0.f, 0.f, 0.f, 0.f, 0.f, 0.f};

  // rows this wave actually needs (p < lenb); wave-uniform
  int rows = lenb - wv * 64;
  if (rows > 64) rows = 64;
  for (int i0 = 0; i0 < rows; i0 += 8) {
    float4 R0[8], R1[8];
    float d8[8];
#pragma unroll
    for (int k = 0; k < 8; ++k) {
      if (i0 + k < rows) {
        int p = wv * 64 + i0 + k;
        const float* row = mem + (size_t)p * DD + lane * 8;
        R0[k] = *(const float4*)(row);
        R1[k] = *(const float4*)(row + 4);
        d8[k] = R0[k].x*va.x + R0[k].y*va.y + R0[k].z*va.z + R0[k].w*va.w
              + R1[k].x*vb.x + R1[k].y*vb.y + R1[k].z*vb.z + R1[k].w*vb.w;
      } else {
        d8[k] = 0.f;
      }
    }
#pragma unroll
    for (int o = 32; o > 0; o >>= 1) {
#pragma unroll
      for (int k = 0; k < 8; ++k) d8[k] += __shfl_xor(d8[k], o);
    }
#pragma unroll
    for (int k = 0; k < 8; ++k) {
      int p = wv * 64 + i0 + k;
      bool live = (i0 + k < rows) && !(p >= s && p < e);
      if (live) {
        float dis = (p < s) ? (float)(s - p) : (float)(p - e + 1);
        float pw = 1.f - dis / seqlen;
        float sc = fast_tanh(pw * d8[k] + c);
        if (sc > m) {
          float scale = __expf(m - sc);
          ssum *= scale;
#pragma unroll
          for (int j = 0; j < 8; ++j) am[j] *= scale;
          m = sc;
        }
        float u = __expf(sc - m);
        ssum += u;
        float upw = u * pw;
        am[0] += upw * R0[k].x; am[1] += upw * R0[k].y; am[2] += upw * R0[k].z; am[3] += upw * R0[k].w;
        am[4] += upw * R1[k].x; am[5] += upw * R1[k].y; am[6] += upw * R1[k].z; am[7] += upw * R1[k].w;
      }
    }
  }
  if (lane == 0) { mstate[wv][0] = m; mstate[wv][1] = ssum; }
  __syncthreads();
  float M = fmaxf(fmaxf(mstate[0][0], mstate[1][0]), fmaxf(mstate[2][0], mstate[3][0]));
  float S = mstate[0][1] * __expf(mstate[0][0] - M)
          + mstate[1][1] * __expf(mstate[1][0] - M)
          + mstate[2][1] * __expf(mstate[2][0] - M)
          + mstate[3][1] * __expf(mstate[3][0] - M);
  float ew = __expf(m - M);
  {
    float4 s0 = make_float4(am[0] * ew, am[1] * ew, am[2] * ew, am[3] * ew);
    float4 s1 = make_float4(am[4] * ew, am[5] * ew, am[6] * ew, am[7] * ew);
    *(float4*)(&buf[wv][lane * 8]) = s0;
    *(float4*)(&buf[wv][lane * 8 + 4]) = s1;
  }
  __syncthreads();
  {
    int d0 = t * 2;
    float inv = 1.f / S;
    mix_lds[d0]     = (buf[0][d0] + buf[1][d0] + buf[2][d0] + buf[3][d0]) * inv;
    mix_lds[d0 + 1] = (buf[0][d0 + 1] + buf[1][d0 + 1] + buf[2][d0 + 1] + buf[3][d0 + 1]) * inv;
  }
  __syncthreads();

  // ---- logits + log_softmax ----
  float vals[8];
  int idx = t * 8;
  if (idx < K3) {
    const float* sp = span + (size_t)f * K3 + idx;
    float4 x0 = *(const float4*)(sp);
    float4 x1 = *(const float4*)(sp + 4);
    vals[0]=x0.x; vals[1]=x0.y; vals[2]=x0.z; vals[3]=x0.w;
    vals[4]=x1.x; vals[5]=x1.y; vals[6]=x1.z; vals[7]=x1.w;
  } else {
#pragma unroll
    for (int j = 0; j < 8; ++j) vals[j] = mix_lds[idx - K3 + j];
  }
  float acc5[TT];
#pragma unroll
  for (int tg = 0; tg < TT; ++tg) {
    const float* twr = tag_w + (size_t)tg * K4 + idx;
    float a = 0.f;
#pragma unroll
    for (int j = 0; j < 8; ++j) a += vals[j] * twr[j];
    acc5[tg] = wave_reduce_sum(a);
  }
  if (lane == 0) {
#pragma unroll
    for (int tg = 0; tg < TT; ++tg) pl[wv * TT + tg] = acc5[tg];
  }
  __syncthreads();
  if (t < TT) {
    l5[t] = pl[t] + pl[TT + t] + pl[2 * TT + t] + pl[3 * TT + t] + tag_b[t];
  }
  __syncthreads();
  if (t == 0) {
    float mm = l5[0];
#pragma unroll
    for (int j = 1; j < TT; ++j) mm = fmaxf(mm, l5[j]);
    float se = 0.f;
#pragma unroll
    for (int j = 0; j < TT; ++j) se += __expf(l5[j] - mm);
    float lse = mm + logf(se);
#pragma unroll
    for (int j = 0; j < TT; ++j) out[(size_t)f * TT + j] = l5[j] - lse;
  }
}

extern "C" void kernel_launch(void* const* d_in, const int* in_sizes, int n_in,
                              void* d_out, int out_size, void* d_ws, size_t ws_size,
                              hipStream_t stream) {
  const float* en      = (const float*)d_in[0];
  const int*   lengths = (const int*)d_in[1];
  const int*   frag_b  = (const int*)d_in[2];
  const int*   frag_s  = (const int*)d_in[3];
  const int*   frag_e  = (const int*)d_in[4];
  const float* att_w   = (const float*)d_in[5];
  const float* att_b   = (const float*)d_in[6];
  const float* tag_w   = (const float*)d_in[7];
  const float* tag_b   = (const float*)d_in[8];
  float* out = (float*)d_out;

  float* span  = (float*)d_ws;                      // F*1536
  float* cvec  = span + (size_t)FF * K3;            // F
  float* vpart = cvec + FF;                         // SK*F*512
  int*   order = (int*)(vpart + (size_t)SK * FF * DD);  // F ints

  bucket_kernel<<<1, FF, 0, stream>>>(frag_b, order);
  span_kernel<<<FF, 128, 0, stream>>>(en, frag_b, frag_s, frag_e, att_b, order, span, cvec);
  gemm_v<<<dim3(8, 16, SK), 256, 0, stream>>>(span, att_w, vpart);
  frag_kernel<<<FF, 256, 0, stream>>>(en, lengths, frag_b, frag_s, frag_e,
                                      span, cvec, vpart, tag_w, tag_b, order, out);
}

// Round 8
// 149.875 us; speedup vs baseline: 1.5906x; 1.0425x over previous
//
#include <hip/hip_runtime.h>
#include <math.h>

#define BB 32
#define SS 256
#define DD 512
#define FF 1024
#define TT 5
#define K3 1536   // 3*D
#define K4 2048   // 4*D
#define GK 1536
#define SK 4      // split-K factor for gemm_v
#define KCH (GK / SK)   // 384

__device__ __forceinline__ float wave_reduce_sum(float x) {
#pragma unroll
  for (int o = 32; o > 0; o >>= 1) x += __shfl_xor(x, o);
  return x;
}

// exp-based tanh: ~8 instrs vs library tanhf's branchy range handling.
__device__ __forceinline__ float fast_tanh(float x) {
  float ax = fabsf(x);
  float t = __expf(-2.f * ax);
  float r = (1.f - t) / (1.f + t);
  return x < 0.f ? -r : r;
}

// ---------------- Kernel 0: bucket fragments by sentence ----------------
__global__ __launch_bounds__(1024)
void bucket_kernel(const int* __restrict__ fb, int* __restrict__ order) {
  __shared__ int cnt[BB];
  __shared__ int start[BB];
  int t = threadIdx.x;
  if (t < BB) cnt[t] = 0;
  __syncthreads();
  int b = fb[t];
  int r = atomicAdd(&cnt[b], 1);
  __syncthreads();
  if (t == 0) {
    int acc = 0;
    for (int i = 0; i < BB; ++i) { start[i] = acc; acc += cnt[i]; }
  }
  __syncthreads();
  order[start[b] + r] = t;
}

// ---------------- Kernel A: span [F,1536] and c[F] (XCD-striped) ----------------
__global__ __launch_bounds__(128)
void span_kernel(const float* __restrict__ en, const int* __restrict__ fb,
                 const int* __restrict__ fs, const int* __restrict__ fe,
                 const float* __restrict__ att_b, const int* __restrict__ order,
                 float* __restrict__ span, float* __restrict__ cvec)
{
  int bid = blockIdx.x;
  int f = order[(bid & 7) * (FF / 8) + (bid >> 3)];
  int t = threadIdx.x;
  int b = fb[f], s = fs[f], e = fe[f];
  const float* base = en + (size_t)b * SS * DD;
  int d0 = t * 4;
  float4 lw = *(const float4*)(base + (size_t)s * DD + d0);
  float4 rw = *(const float4*)(base + (size_t)(e - 1) * DD + d0);
  float4 wsum = make_float4(0.f, 0.f, 0.f, 0.f);
  for (int p = s; p < e; ++p) {
    float4 m = *(const float4*)(base + (size_t)p * DD + d0);
    wsum.x += m.x; wsum.y += m.y; wsum.z += m.z; wsum.w += m.w;
  }
  float* sp = span + (size_t)f * K3;
  *(float4*)(sp + d0) = lw;
  *(float4*)(sp + DD + d0) = wsum;
  *(float4*)(sp + 2 * DD + d0) = rw;
  float4 a0 = *(const float4*)(att_b + d0);
  float4 a1 = *(const float4*)(att_b + DD + d0);
  float4 a2 = *(const float4*)(att_b + 2 * DD + d0);
  float part = lw.x*a0.x + lw.y*a0.y + lw.z*a0.z + lw.w*a0.w
             + wsum.x*a1.x + wsum.y*a1.y + wsum.z*a1.z + wsum.w*a1.w
             + rw.x*a2.x + rw.y*a2.y + rw.z*a2.z + rw.w*a2.w;
  part = wave_reduce_sum(part);
  __shared__ float red[2];
  if ((t & 63) == 0) red[t >> 6] = part;
  __syncthreads();
  if (t == 0) cvec[f] = red[0] + red[1];
}

// ---------------- Kernel B: v partials = span @ att_w, split-K ----------------
// BM=64 BN=64 BK=16, 256 threads, 4x4/thread, register double-buffer:
// prefetch next K-tile's global loads during current tile's FMA loop.
__global__ __launch_bounds__(256)
void gemm_v(const float* __restrict__ A,    // span [1024][1536]
            const float* __restrict__ Bw,   // att_w [1536][512]
            float* __restrict__ Cpart)      // [SK][1024][512]
{
  const int BM = 64, BN = 64, BK = 16;
  const int NIT = KCH / BK;   // 24
  __shared__ float As[BK][BM + 4];
  __shared__ float Bs[BK][BN + 4];
  int t = threadIdx.x;
  int n0 = blockIdx.x * BN;          // grid.x = 8
  int m0 = blockIdx.y * BM;          // grid.y = 16
  int kbase = blockIdx.z * KCH;

  int ar = t >> 2;          // 0..63  A row
  int ac = (t & 3) * 4;     // 0,4,8,12
  int br = t >> 4;          // 0..15  B k-row
  int bc = (t & 15) * 4;    // 0..60
  int tm = (t >> 4) * 4;    // 0..60
  int tn = (t & 15) * 4;    // 0..60

  float acc[4][4] = {};

  const float* Aptr = A  + (size_t)(m0 + ar) * GK + kbase + ac;
  const float* Bptr = Bw + (size_t)(kbase + br) * DD + n0 + bc;

  float4 av = *(const float4*)(Aptr);
  float4 bv = *(const float4*)(Bptr);

  for (int it = 0; it < NIT; ++it) {
    __syncthreads();                 // previous compute done reading LDS
    As[ac + 0][ar] = av.x;
    As[ac + 1][ar] = av.y;
    As[ac + 2][ar] = av.z;
    As[ac + 3][ar] = av.w;
    *(float4*)(&Bs[br][bc]) = bv;
    __syncthreads();                 // stores visible
    if (it + 1 < NIT) {              // prefetch next tile (overlaps compute)
      av = *(const float4*)(Aptr + (it + 1) * BK);
      bv = *(const float4*)(Bptr + (size_t)(it + 1) * BK * DD);
    }
#pragma unroll
    for (int k = 0; k < BK; ++k) {
      float4 a = *(float4*)(&As[k][tm]);
      float4 b = *(float4*)(&Bs[k][tn]);
      acc[0][0] += a.x * b.x; acc[0][1] += a.x * b.y; acc[0][2] += a.x * b.z; acc[0][3] += a.x * b.w;
      acc[1][0] += a.y * b.x; acc[1][1] += a.y * b.y; acc[1][2] += a.y * b.z; acc[1][3] += a.y * b.w;
      acc[2][0] += a.z * b.x; acc[2][1] += a.z * b.y; acc[2][2] += a.z * b.z; acc[2][3] += a.z * b.w;
      acc[3][0] += a.w * b.x; acc[3][1] += a.w * b.y; acc[3][2] += a.w * b.z; acc[3][3] += a.w * b.w;
    }
  }
  float* Cp = Cpart + (size_t)blockIdx.z * FF * DD;
#pragma unroll
  for (int i = 0; i < 4; ++i) {
    *(float4*)(Cp + (size_t)(m0 + tm + i) * DD + n0 + tn) =
        make_float4(acc[i][0], acc[i][1], acc[i][2], acc[i][3]);
  }
}

// ---------------- Kernel C: fused single-pass per-fragment ----------------
// FIXED-MAX softmax: scores = tanh(..) <= 1, so use m=1.0 always. exp(sc-1)
// in [e^-2, 1] for live rows — no overflow; identical after normalization
// (constant factor cancels). Removes the serial per-row rescale chain.
__global__ __launch_bounds__(256)
void frag_kernel(const float* __restrict__ en, const int* __restrict__ lengths,
                 const int* __restrict__ fb, const int* __restrict__ fs,
                 const int* __restrict__ fe,
                 const float* __restrict__ span, const float* __restrict__ cvec,
                 const float* __restrict__ vpart,
                 const float* __restrict__ tag_w, const float* __restrict__ tag_b,
                 const int* __restrict__ order,
                 float* __restrict__ out)
{
  __shared__ float v_lds[DD];
  __shared__ float buf[4][DD];
  __shared__ float wsum[4];
  __shared__ float mix_lds[DD];
  __shared__ float pl[4 * TT];
  __shared__ float l5[TT];

  int bid = blockIdx.x;
  int f = order[(bid & 7) * (FF / 8) + (bid >> 3)];
  int t = threadIdx.x;
  int lane = t & 63, wv = t >> 6;
  int b = fb[f], s = fs[f], e = fe[f];
  int lenb = lengths[b];
  float seqlen = (float)lengths[0];
  float invseq = 1.f / seqlen;
  float c = cvec[f];
  const float* mem = en + (size_t)b * SS * DD;

  if (t < 128) {
    float4 v0 = *(const float4*)(vpart + (size_t)f * DD + t * 4);
    float4 v1 = *(const float4*)(vpart + (size_t)FF * DD + (size_t)f * DD + t * 4);
    float4 v2 = *(const float4*)(vpart + 2 * (size_t)FF * DD + (size_t)f * DD + t * 4);
    float4 v3 = *(const float4*)(vpart + 3 * (size_t)FF * DD + (size_t)f * DD + t * 4);
    *(float4*)(v_lds + t * 4) = make_float4(v0.x + v1.x + v2.x + v3.x,
                                            v0.y + v1.y + v2.y + v3.y,
                                            v0.z + v1.z + v2.z + v3.z,
                                            v0.w + v1.w + v2.w + v3.w);
  }
  __syncthreads();

  float4 va = *(float4*)(v_lds + lane * 8);
  float4 vb = *(float4*)(v_lds + lane * 8 + 4);
  float ssum = 0.f;
  float am[8] = {0.f, 0.f, 0.f, 0.f, 0.f, 0.f, 0.f, 0.f};

  // rows this wave actually needs (p < lenb); wave-uniform
  int rows = lenb - wv * 64;
  if (rows > 64) rows = 64;
  for (int i0 = 0; i0 < rows; i0 += 8) {
    float4 R0[8], R1[8];
    float d8[8];
#pragma unroll
    for (int k = 0; k < 8; ++k) {
      if (i0 + k < rows) {
        int p = wv * 64 + i0 + k;
        const float* row = mem + (size_t)p * DD + lane * 8;
        R0[k] = *(const float4*)(row);
        R1[k] = *(const float4*)(row + 4);
        d8[k] = R0[k].x*va.x + R0[k].y*va.y + R0[k].z*va.z + R0[k].w*va.w
              + R1[k].x*vb.x + R1[k].y*vb.y + R1[k].z*vb.z + R1[k].w*vb.w;
      } else {
        d8[k] = 0.f;
      }
    }
#pragma unroll
    for (int o = 32; o > 0; o >>= 1) {
#pragma unroll
      for (int k = 0; k < 8; ++k) d8[k] += __shfl_xor(d8[k], o);
    }
#pragma unroll
    for (int k = 0; k < 8; ++k) {
      int p = wv * 64 + i0 + k;
      bool live = (i0 + k < rows) && !(p >= s && p < e);
      if (live) {
        float dis = (p < s) ? (float)(s - p) : (float)(p - e + 1);
        float pw = 1.f - dis * invseq;
        float sc = fast_tanh(pw * d8[k] + c);
        float u = __expf(sc - 1.f);       // fixed max = 1 (tanh bound)
        ssum += u;
        float upw = u * pw;
        am[0] += upw * R0[k].x; am[1] += upw * R0[k].y; am[2] += upw * R0[k].z; am[3] += upw * R0[k].w;
        am[4] += upw * R1[k].x; am[5] += upw * R1[k].y; am[6] += upw * R1[k].z; am[7] += upw * R1[k].w;
      }
    }
  }
  if (lane == 0) wsum[wv] = ssum;
  *(float4*)(&buf[wv][lane * 8])     = make_float4(am[0], am[1], am[2], am[3]);
  *(float4*)(&buf[wv][lane * 8 + 4]) = make_float4(am[4], am[5], am[6], am[7]);
  __syncthreads();
  {
    float S = wsum[0] + wsum[1] + wsum[2] + wsum[3];
    float inv = 1.f / S;
    int d0 = t * 2;
    mix_lds[d0]     = (buf[0][d0] + buf[1][d0] + buf[2][d0] + buf[3][d0]) * inv;
    mix_lds[d0 + 1] = (buf[0][d0 + 1] + buf[1][d0 + 1] + buf[2][d0 + 1] + buf[3][d0 + 1]) * inv;
  }
  __syncthreads();

  // ---- logits + log_softmax ----
  float vals[8];
  int idx = t * 8;
  if (idx < K3) {
    const float* sp = span + (size_t)f * K3 + idx;
    float4 x0 = *(const float4*)(sp);
    float4 x1 = *(const float4*)(sp + 4);
    vals[0]=x0.x; vals[1]=x0.y; vals[2]=x0.z; vals[3]=x0.w;
    vals[4]=x1.x; vals[5]=x1.y; vals[6]=x1.z; vals[7]=x1.w;
  } else {
#pragma unroll
    for (int j = 0; j < 8; ++j) vals[j] = mix_lds[idx - K3 + j];
  }
  float acc5[TT];
#pragma unroll
  for (int tg = 0; tg < TT; ++tg) {
    const float* twr = tag_w + (size_t)tg * K4 + idx;
    float a = 0.f;
#pragma unroll
    for (int j = 0; j < 8; ++j) a += vals[j] * twr[j];
    acc5[tg] = wave_reduce_sum(a);
  }
  if (lane == 0) {
#pragma unroll
    for (int tg = 0; tg < TT; ++tg) pl[wv * TT + tg] = acc5[tg];
  }
  __syncthreads();
  if (t < TT) {
    l5[t] = pl[t] + pl[TT + t] + pl[2 * TT + t] + pl[3 * TT + t] + tag_b[t];
  }
  __syncthreads();
  if (t == 0) {
    float mm = l5[0];
#pragma unroll
    for (int j = 1; j < TT; ++j) mm = fmaxf(mm, l5[j]);
    float se = 0.f;
#pragma unroll
    for (int j = 0; j < TT; ++j) se += __expf(l5[j] - mm);
    float lse = mm + logf(se);
#pragma unroll
    for (int j = 0; j < TT; ++j) out[(size_t)f * TT + j] = l5[j] - lse;
  }
}

extern "C" void kernel_launch(void* const* d_in, const int* in_sizes, int n_in,
                              void* d_out, int out_size, void* d_ws, size_t ws_size,
                              hipStream_t stream) {
  const float* en      = (const float*)d_in[0];
  const int*   lengths = (const int*)d_in[1];
  const int*   frag_b  = (const int*)d_in[2];
  const int*   frag_s  = (const int*)d_in[3];
  const int*   frag_e  = (const int*)d_in[4];
  const float* att_w   = (const float*)d_in[5];
  const float* att_b   = (const float*)d_in[6];
  const float* tag_w   = (const float*)d_in[7];
  const float* tag_b   = (const float*)d_in[8];
  float* out = (float*)d_out;

  float* span  = (float*)d_ws;                      // F*1536
  float* cvec  = span + (size_t)FF * K3;            // F
  float* vpart = cvec + FF;                         // SK*F*512
  int*   order = (int*)(vpart + (size_t)SK * FF * DD);  // F ints

  bucket_kernel<<<1, FF, 0, stream>>>(frag_b, order);
  span_kernel<<<FF, 128, 0, stream>>>(en, frag_b, frag_s, frag_e, att_b, order, span, cvec);
  gemm_v<<<dim3(8, 16, SK), 256, 0, stream>>>(span, att_w, vpart);
  frag_kernel<<<FF, 256, 0, stream>>>(en, lengths, frag_b, frag_s, frag_e,
                                      span, cvec, vpart, tag_w, tag_b, order, out);
}